// Round 4
// baseline (888.625 us; speedup 1.0000x reference)
//
#include <hip/hip_runtime.h>
#include <stdint.h>

// STGraphConstructor: C[b] = tanh(relu(E[b] @ E[b]^T)), E = concat(spatial, temporal)
// B=16, N=2048, T=168, D=64, M=2216. fp32 in/out.
// R9: DIAGNOSTIC round. R8 structure, but the row-panel compute+store loop runs
// 5x (identical values rewritten -> bit-identical output). Purpose: our dispatch
// never appears in the rocprof top-5 (the harness's ~240us fills crowd it out),
// so we have no counters for our own kernel and cannot discriminate:
//   Model A: kernel ~170us, writes at ~1.9 TB/s (address-pattern inefficiency)
//   Model B: kernel ~60us (at write roofline), ~100us of tiny reset dispatches
//            hidden in the timed graph.
// 5x repeat forces our dispatch above the fills under either model, yielding
// dur/hbm_gbps/FETCH/WRITE/VALUBusy/Occupancy for the stgraph dispatch itself.
// Expected dur regression is deliberate; next round restores the best kernel.

constexpr int Bsz = 16;
constexpr int Nsp = 2048;
constexpr int Ttm = 168;
constexpr int D   = 64;
constexpr int M   = Nsp + Ttm;                // 2216
constexpr int NG32 = (M + 31) / 32;           // 70 row/col groups of 32
constexpr int NG   = 72;                      // groups allocated in ws (zero-padded)
constexpr int GRP_SH   = 4 * 64 * 8;          // shorts per group: 4 ks * 64 lanes * 8
constexpr int BATCH_SH = NG * GRP_SH;         // 147456 shorts / batch / plane
constexpr int PLANE_SH = Bsz * BATCH_SH;      // 2359296 shorts / plane
constexpr size_t WS_NEED = (size_t)2 * PLANE_SH * sizeof(unsigned short); // 9.4 MB
constexpr int REPEAT = 5;                     // diagnostic work multiplier

typedef __attribute__((ext_vector_type(8)))  short bf16x8;   // 8 bf16 = 4 VGPRs
typedef __attribute__((ext_vector_type(16))) float f32x16;   // 32x32 acc

__device__ inline void split8(const float4& a, const float4& b,
                              bf16x8& hi, bf16x8& lo) {
    float x[8] = {a.x, a.y, a.z, a.w, b.x, b.y, b.z, b.w};
    #pragma unroll
    for (int i = 0; i < 8; ++i) {
        union { float f; uint32_t u; } v; v.f = x[i];
        uint32_t hu = (v.u + 0x7FFFu + ((v.u >> 16) & 1u)) >> 16;   // RNE to bf16
        union { uint32_t u; float f; } hf; hf.u = hu << 16;
        union { float f; uint32_t u; } r; r.f = x[i] - hf.f;        // exact residual
        uint32_t lu = (r.u + 0x7FFFu + ((r.u >> 16) & 1u)) >> 16;
        hi[i] = (short)hu;
        lo[i] = (short)lu;
    }
}

__device__ inline float act_tanh_relu(float x) {
    const float xr = fmaxf(x, 0.0f);
    const float e  = __expf(2.0f * xr);                  // inf for large x -> 1
    const float r  = __builtin_amdgcn_rcpf(e + 1.0f);    // ~1 ulp, rcp(inf)=0
    return 1.0f - 2.0f * r;
}

// ---------------- kernel 1: fp32 E -> swizzled hi/lo bf16 planes ----------------
__global__ __launch_bounds__(256) void convert_kernel(
    const float* __restrict__ spatial,
    const float* __restrict__ temporal,
    unsigned short* __restrict__ ws)
{
    const int idx = blockIdx.x * 256 + threadIdx.x;   // 0 .. 16*72*4*64-1
    const int b  = idx / (NG * 4 * 64);
    const int r1 = idx % (NG * 4 * 64);
    const int g  = r1 / (4 * 64);
    const int r2 = r1 % (4 * 64);
    const int ks   = r2 >> 6;
    const int lane = r2 & 63;
    const int row  = 32 * g + (lane & 31);
    const int k0   = ks * 16 + 8 * (lane >> 5);

    float4 v0 = make_float4(0.f, 0.f, 0.f, 0.f), v1 = v0;
    if (row < M) {
        const float* src = (row < Nsp)
            ? spatial  + ((size_t)b * Nsp + row) * D
            : temporal + ((size_t)b * Ttm + (row - Nsp)) * D;
        v0 = *(const float4*)(src + k0);
        v1 = *(const float4*)(src + k0 + 4);
    }
    bf16x8 hi, lo;
    split8(v0, v1, hi, lo);

    const size_t o = (size_t)b * BATCH_SH + (size_t)g * GRP_SH + (ks * 64 + lane) * 8;
    *(bf16x8*)(ws + o)            = hi;
    *(bf16x8*)(ws + PLANE_SH + o) = lo;
}

// ---------------- kernel 2: row-panel MFMA main (5x diagnostic repeat) ----------------
__global__ __launch_bounds__(256, 4) void stgraph_rowpanel(
    const unsigned short* __restrict__ ws,
    float* __restrict__ out)
{
    const int tid = threadIdx.x;
    const int g   = blockIdx.x;      // row group: panel rows 32g..32g+31
    const int b   = blockIdx.y;

    const int lane = tid & 63;
    const int w    = tid >> 6;
    const int l31  = lane & 31;
    const int lhi  = lane >> 5;

    const unsigned short* Hb = ws + (size_t)b * BATCH_SH;
    const unsigned short* Lb = Hb + PLANE_SH;

    // A fragments for this block's panel (all waves share the same 32 rows)
    bf16x8 ahi[4], alo[4];
    #pragma unroll
    for (int ks = 0; ks < 4; ++ks) {
        const int fo = (ks * 64 + lane) * 8;
        ahi[ks] = *(const bf16x8*)(Hb + (size_t)g * GRP_SH + fo);
        alo[ks] = *(const bf16x8*)(Lb + (size_t)g * GRP_SH + fo);
    }

    float* out_b = out + (size_t)b * M * M;

    #pragma unroll 1
    for (int pass = 0; pass < REPEAT; ++pass) {
        for (int ct = w; ct < NG32; ct += 4) {
            f32x16 acc = {};
            #pragma unroll
            for (int ks = 0; ks < 4; ++ks) {
                const int fo = (ks * 64 + lane) * 8;
                bf16x8 bhi = *(const bf16x8*)(Hb + (size_t)ct * GRP_SH + fo);
                bf16x8 blo = *(const bf16x8*)(Lb + (size_t)ct * GRP_SH + fo);
                acc = __builtin_amdgcn_mfma_f32_32x32x16_bf16(ahi[ks], bhi, acc, 0, 0, 0);
                acc = __builtin_amdgcn_mfma_f32_32x32x16_bf16(ahi[ks], blo, acc, 0, 0, 0);
                acc = __builtin_amdgcn_mfma_f32_32x32x16_bf16(alo[ks], bhi, acc, 0, 0, 0);
            }

            // C layout (m74/m101): col = lane&31, row = (r&3) + 8*(r>>2) + 4*lhi
            const int col = 32 * ct + l31;
            if (col < M) {
                #pragma unroll
                for (int r = 0; r < 16; ++r) {
                    const int grow = 32 * g + (r & 3) + 8 * (r >> 2) + 4 * lhi;
                    if (grow < M)
                        out_b[(size_t)grow * M + col] = act_tanh_relu(acc[r]);
                }
            }
        }
    }
}

// ---------------- fallback (R6, self-contained) if ws too small ----------------
constexpr int TILE = 128;
constexpr int NT   = (M + TILE - 1) / TILE;   // 18 tiles
constexpr int NPAIR = NT * (NT + 1) / 2;      // 171 pairs

__global__ __launch_bounds__(256, 3) void stgraph_fallback(
    const float* __restrict__ spatial,
    const float* __restrict__ temporal,
    float* __restrict__ out)
{
    const int tid = threadIdx.x;
    const int b   = blockIdx.y;
    const int p = blockIdx.x;
    int ti = (int)((37.0f - sqrtf(1369.0f - 8.0f * (float)p)) * 0.5f);
    while (ti * (37 - ti) / 2 > p) --ti;
    while ((ti + 1) * (36 - ti) / 2 <= p) ++ti;
    const int tj = ti + (p - ti * (37 - ti) / 2);
    const bool diag = (ti == tj);

    const float* sp_b = spatial  + (size_t)b * Nsp * D;
    const float* tp_b = temporal + (size_t)b * Ttm * D;

    const int lane = tid & 63;
    const int w    = tid >> 6;
    const int l31  = lane & 31;
    const int lhi  = lane >> 5;

    const int giA = ti * TILE + 32 * w + l31;
    const float* rowA = nullptr;
    if (giA < M)
        rowA = (giA < Nsp) ? sp_b + (size_t)giA * D
                           : tp_b + (size_t)(giA - Nsp) * D;
    const float* rowB[4];
    #pragma unroll
    for (int t = 0; t < 4; ++t) {
        const int gj = tj * TILE + 32 * t + l31;
        rowB[t] = nullptr;
        if (gj < M)
            rowB[t] = (gj < Nsp) ? sp_b + (size_t)gj * D
                                 : tp_b + (size_t)(gj - Nsp) * D;
    }

    f32x16 acc[4] = {};
    #pragma unroll
    for (int ks = 0; ks < 4; ++ks) {
        const int ko = ks * 16 + 8 * lhi;
        float4 a0 = make_float4(0.f, 0.f, 0.f, 0.f), a1 = a0;
        if (rowA) { a0 = *(const float4*)(rowA + ko); a1 = *(const float4*)(rowA + ko + 4); }
        bf16x8 ahi, alo;
        split8(a0, a1, ahi, alo);
        #pragma unroll
        for (int t = 0; t < 4; ++t) {
            float4 b0 = make_float4(0.f, 0.f, 0.f, 0.f), b1 = b0;
            if (rowB[t]) { b0 = *(const float4*)(rowB[t] + ko); b1 = *(const float4*)(rowB[t] + ko + 4); }
            bf16x8 bhi, blo;
            split8(b0, b1, bhi, blo);
            acc[t] = __builtin_amdgcn_mfma_f32_32x32x16_bf16(ahi, bhi, acc[t], 0, 0, 0);
            acc[t] = __builtin_amdgcn_mfma_f32_32x32x16_bf16(ahi, blo, acc[t], 0, 0, 0);
            acc[t] = __builtin_amdgcn_mfma_f32_32x32x16_bf16(alo, bhi, acc[t], 0, 0, 0);
        }
    }

    float* out_b = out + (size_t)b * M * M;
    #pragma unroll
    for (int t = 0; t < 4; ++t) {
        const int gj = tj * TILE + 32 * t + l31;
        float v[16];
        #pragma unroll
        for (int r = 0; r < 16; ++r) v[r] = act_tanh_relu(acc[t][r]);
        if (gj < M) {
            #pragma unroll
            for (int r = 0; r < 16; ++r) {
                const int gi = ti * TILE + 32 * w + (r & 3) + 8 * (r >> 2) + 4 * lhi;
                if (gi < M) out_b[(size_t)gi * M + gj] = v[r];
            }
            if (!diag) {
                #pragma unroll
                for (int gq = 0; gq < 4; ++gq) {
                    const int gibase = ti * TILE + 32 * w + 8 * gq + 4 * lhi;
                    float4 w4 = make_float4(v[4 * gq + 0], v[4 * gq + 1],
                                            v[4 * gq + 2], v[4 * gq + 3]);
                    *(float4*)(&out_b[(size_t)gj * M + gibase]) = w4;
                }
            }
        }
    }
}

extern "C" void kernel_launch(void* const* d_in, const int* in_sizes, int n_in,
                              void* d_out, int out_size, void* d_ws, size_t ws_size,
                              hipStream_t stream) {
    const float* spatial  = (const float*)d_in[0];
    const float* temporal = (const float*)d_in[1];
    float* out = (float*)d_out;

    if (d_ws != nullptr && ws_size >= WS_NEED) {
        unsigned short* ws = (unsigned short*)d_ws;
        {
            dim3 block(256);
            dim3 grid((Bsz * NG * 4 * 64) / 256);   // 1152 blocks
            convert_kernel<<<grid, block, 0, stream>>>(spatial, temporal, ws);
        }
        {
            dim3 block(256);
            dim3 grid(NG32, Bsz);                   // 70 x 16 row panels
            stgraph_rowpanel<<<grid, block, 0, stream>>>(ws, out);
        }
    } else {
        dim3 block(256);
        dim3 grid(NPAIR, Bsz);
        stgraph_fallback<<<grid, block, 0, stream>>>(spatial, temporal, out);
    }
}

// Round 5
// 460.049 us; speedup vs baseline: 1.9316x; 1.9316x over previous
//
#include <hip/hip_runtime.h>
#include <stdint.h>

// STGraphConstructor: C[b] = tanh(relu(E[b] @ E[b]^T)), E = concat(spatial, temporal)
// B=16, N=2048, T=168, D=64, M=2216. fp32 in/out.
// R10: latency attack, guided by R9's diagnostic counters:
//   FETCH 86MB/pass (9x the 9.4MB ws!) -> write stream evicts B-frags from L2,
//   loads run at HBM latency; MfmaUtil 10%, VALUBusy 22%, Occupancy 36%
//   (grid-limited: 1120 blocks = 4.4/CU). Nothing busy => latency-bound.
// Fixes (all one diagnosis, store pattern unchanged from R8):
//   1. Nontemporal stores: output is write-once -> don't let 337MB stream
//      thrash the 4MB/XCD L2 that should hold ws fragments.
//   2. XCD b-clustering: flat 2240-block grid, b = 2*(lid&7)+((lid>>3)&1)
//      (round-robin block->XCD assumed) -> each XCD serves 2 batches,
//      ws working set 2.3MB < 4MB L2.
//   3. 2x occupancy: col range split in halves -> 2240 blocks (8.75/CU),
//      __launch_bounds__(256,8); 48-VGPR kernel supports 32 waves/CU.
// Numerics bit-identical to R5-R9.

constexpr int Bsz = 16;
constexpr int Nsp = 2048;
constexpr int Ttm = 168;
constexpr int D   = 64;
constexpr int M   = Nsp + Ttm;                // 2216
constexpr int NG32 = (M + 31) / 32;           // 70 row/col groups of 32
constexpr int NG   = 72;                      // groups allocated in ws (zero-padded)
constexpr int GRP_SH   = 4 * 64 * 8;          // shorts per group: 4 ks * 64 lanes * 8
constexpr int BATCH_SH = NG * GRP_SH;         // 147456 shorts / batch / plane
constexpr int PLANE_SH = Bsz * BATCH_SH;      // 2359296 shorts / plane
constexpr size_t WS_NEED = (size_t)2 * PLANE_SH * sizeof(unsigned short); // 9.4 MB

typedef __attribute__((ext_vector_type(8)))  short bf16x8;   // 8 bf16 = 4 VGPRs
typedef __attribute__((ext_vector_type(16))) float f32x16;   // 32x32 acc

__device__ inline void split8(const float4& a, const float4& b,
                              bf16x8& hi, bf16x8& lo) {
    float x[8] = {a.x, a.y, a.z, a.w, b.x, b.y, b.z, b.w};
    #pragma unroll
    for (int i = 0; i < 8; ++i) {
        union { float f; uint32_t u; } v; v.f = x[i];
        uint32_t hu = (v.u + 0x7FFFu + ((v.u >> 16) & 1u)) >> 16;   // RNE to bf16
        union { uint32_t u; float f; } hf; hf.u = hu << 16;
        union { float f; uint32_t u; } r; r.f = x[i] - hf.f;        // exact residual
        uint32_t lu = (r.u + 0x7FFFu + ((r.u >> 16) & 1u)) >> 16;
        hi[i] = (short)hu;
        lo[i] = (short)lu;
    }
}

__device__ inline float act_tanh_relu(float x) {
    const float xr = fmaxf(x, 0.0f);
    const float e  = __expf(2.0f * xr);                  // inf for large x -> 1
    const float r  = __builtin_amdgcn_rcpf(e + 1.0f);    // ~1 ulp, rcp(inf)=0
    return 1.0f - 2.0f * r;
}

// ---------------- kernel 1: fp32 E -> swizzled hi/lo bf16 planes ----------------
__global__ __launch_bounds__(256) void convert_kernel(
    const float* __restrict__ spatial,
    const float* __restrict__ temporal,
    unsigned short* __restrict__ ws)
{
    const int idx = blockIdx.x * 256 + threadIdx.x;   // 0 .. 16*72*4*64-1
    const int b  = idx / (NG * 4 * 64);
    const int r1 = idx % (NG * 4 * 64);
    const int g  = r1 / (4 * 64);
    const int r2 = r1 % (4 * 64);
    const int ks   = r2 >> 6;
    const int lane = r2 & 63;
    const int row  = 32 * g + (lane & 31);
    const int k0   = ks * 16 + 8 * (lane >> 5);

    float4 v0 = make_float4(0.f, 0.f, 0.f, 0.f), v1 = v0;
    if (row < M) {
        const float* src = (row < Nsp)
            ? spatial  + ((size_t)b * Nsp + row) * D
            : temporal + ((size_t)b * Ttm + (row - Nsp)) * D;
        v0 = *(const float4*)(src + k0);
        v1 = *(const float4*)(src + k0 + 4);
    }
    bf16x8 hi, lo;
    split8(v0, v1, hi, lo);

    const size_t o = (size_t)b * BATCH_SH + (size_t)g * GRP_SH + (ks * 64 + lane) * 8;
    *(bf16x8*)(ws + o)            = hi;
    *(bf16x8*)(ws + PLANE_SH + o) = lo;
}

// ---------------- kernel 2: row-panel MFMA main (R10) ----------------
// flat grid of 2240 blocks: (b clustered per XCD) x (70 row groups) x (2 col halves)
__global__ __launch_bounds__(256, 8) void stgraph_rowpanel(
    const unsigned short* __restrict__ ws,
    float* __restrict__ out)
{
    const int tid = threadIdx.x;
    const int lid = blockIdx.x;                  // 0..2239
    // XCD b-clustering: round-robin dispatch assumed (lid % 8 -> XCD).
    // Each XCD then serves b in {2*xcd, 2*xcd+1}: ws slice 2.3MB < 4MB L2.
    const int b  = 2 * (lid & 7) + ((lid >> 3) & 1);
    const int r  = lid >> 4;                     // 0..139
    const int g  = r % NG32;                     // row group: rows 32g..32g+31
    const int h  = r / NG32;                     // col half
    const int lo = h * 35;
    const int hi = lo + 35;                      // [lo, hi) col groups

    const int lane = tid & 63;
    const int w    = tid >> 6;
    const int l31  = lane & 31;
    const int lhi  = lane >> 5;

    const unsigned short* Hb = ws + (size_t)b * BATCH_SH;
    const unsigned short* Lb = Hb + PLANE_SH;

    // A fragments for this block's panel (all waves share the same 32 rows)
    bf16x8 ahi[4], alo[4];
    #pragma unroll
    for (int ks = 0; ks < 4; ++ks) {
        const int fo = (ks * 64 + lane) * 8;
        ahi[ks] = *(const bf16x8*)(Hb + (size_t)g * GRP_SH + fo);
        alo[ks] = *(const bf16x8*)(Lb + (size_t)g * GRP_SH + fo);
    }

    float* out_b = out + (size_t)b * M * M;

    // wave w walks ct = lo+w, lo+w+4, ... within its half.
    for (int ct = lo + w; ct < hi; ct += 4) {
        f32x16 acc = {};
        #pragma unroll
        for (int ks = 0; ks < 4; ++ks) {
            const int fo = (ks * 64 + lane) * 8;
            bf16x8 bhi = *(const bf16x8*)(Hb + (size_t)ct * GRP_SH + fo);
            bf16x8 blo = *(const bf16x8*)(Lb + (size_t)ct * GRP_SH + fo);
            acc = __builtin_amdgcn_mfma_f32_32x32x16_bf16(ahi[ks], bhi, acc, 0, 0, 0);
            acc = __builtin_amdgcn_mfma_f32_32x32x16_bf16(ahi[ks], blo, acc, 0, 0, 0);
            acc = __builtin_amdgcn_mfma_f32_32x32x16_bf16(alo[ks], bhi, acc, 0, 0, 0);
        }

        // C layout (m74/m101): col = lane&31, row = (r&3) + 8*(r>>2) + 4*lhi
        const int col = 32 * ct + l31;
        if (col < M) {
            #pragma unroll
            for (int rr = 0; rr < 16; ++rr) {
                const int grow = 32 * g + (rr & 3) + 8 * (rr >> 2) + 4 * lhi;
                if (grow < M) {
                    // nontemporal: write-once stream, keep it out of L2 so the
                    // ws fragments stay resident.
                    __builtin_nontemporal_store(act_tanh_relu(acc[rr]),
                                                &out_b[(size_t)grow * M + col]);
                }
            }
        }
    }
}

// ---------------- fallback (R6, self-contained) if ws too small ----------------
constexpr int TILE = 128;
constexpr int NT   = (M + TILE - 1) / TILE;   // 18 tiles
constexpr int NPAIR = NT * (NT + 1) / 2;      // 171 pairs

__global__ __launch_bounds__(256, 3) void stgraph_fallback(
    const float* __restrict__ spatial,
    const float* __restrict__ temporal,
    float* __restrict__ out)
{
    const int tid = threadIdx.x;
    const int b   = blockIdx.y;
    const int p = blockIdx.x;
    int ti = (int)((37.0f - sqrtf(1369.0f - 8.0f * (float)p)) * 0.5f);
    while (ti * (37 - ti) / 2 > p) --ti;
    while ((ti + 1) * (36 - ti) / 2 <= p) ++ti;
    const int tj = ti + (p - ti * (37 - ti) / 2);
    const bool diag = (ti == tj);

    const float* sp_b = spatial  + (size_t)b * Nsp * D;
    const float* tp_b = temporal + (size_t)b * Ttm * D;

    const int lane = tid & 63;
    const int w    = tid >> 6;
    const int l31  = lane & 31;
    const int lhi  = lane >> 5;

    const int giA = ti * TILE + 32 * w + l31;
    const float* rowA = nullptr;
    if (giA < M)
        rowA = (giA < Nsp) ? sp_b + (size_t)giA * D
                           : tp_b + (size_t)(giA - Nsp) * D;
    const float* rowB[4];
    #pragma unroll
    for (int t = 0; t < 4; ++t) {
        const int gj = tj * TILE + 32 * t + l31;
        rowB[t] = nullptr;
        if (gj < M)
            rowB[t] = (gj < Nsp) ? sp_b + (size_t)gj * D
                                 : tp_b + (size_t)(gj - Nsp) * D;
    }

    f32x16 acc[4] = {};
    #pragma unroll
    for (int ks = 0; ks < 4; ++ks) {
        const int ko = ks * 16 + 8 * lhi;
        float4 a0 = make_float4(0.f, 0.f, 0.f, 0.f), a1 = a0;
        if (rowA) { a0 = *(const float4*)(rowA + ko); a1 = *(const float4*)(rowA + ko + 4); }
        bf16x8 ahi, alo;
        split8(a0, a1, ahi, alo);
        #pragma unroll
        for (int t = 0; t < 4; ++t) {
            float4 b0 = make_float4(0.f, 0.f, 0.f, 0.f), b1 = b0;
            if (rowB[t]) { b0 = *(const float4*)(rowB[t] + ko); b1 = *(const float4*)(rowB[t] + ko + 4); }
            bf16x8 bhi, blo;
            split8(b0, b1, bhi, blo);
            acc[t] = __builtin_amdgcn_mfma_f32_32x32x16_bf16(ahi, bhi, acc[t], 0, 0, 0);
            acc[t] = __builtin_amdgcn_mfma_f32_32x32x16_bf16(ahi, blo, acc[t], 0, 0, 0);
            acc[t] = __builtin_amdgcn_mfma_f32_32x32x16_bf16(alo, bhi, acc[t], 0, 0, 0);
        }
    }

    float* out_b = out + (size_t)b * M * M;
    #pragma unroll
    for (int t = 0; t < 4; ++t) {
        const int gj = tj * TILE + 32 * t + l31;
        float v[16];
        #pragma unroll
        for (int r = 0; r < 16; ++r) v[r] = act_tanh_relu(acc[t][r]);
        if (gj < M) {
            #pragma unroll
            for (int r = 0; r < 16; ++r) {
                const int gi = ti * TILE + 32 * w + (r & 3) + 8 * (r >> 2) + 4 * lhi;
                if (gi < M) out_b[(size_t)gi * M + gj] = v[r];
            }
            if (!diag) {
                #pragma unroll
                for (int gq = 0; gq < 4; ++gq) {
                    const int gibase = ti * TILE + 32 * w + 8 * gq + 4 * lhi;
                    float4 w4 = make_float4(v[4 * gq + 0], v[4 * gq + 1],
                                            v[4 * gq + 2], v[4 * gq + 3]);
                    *(float4*)(&out_b[(size_t)gj * M + gibase]) = w4;
                }
            }
        }
    }
}

extern "C" void kernel_launch(void* const* d_in, const int* in_sizes, int n_in,
                              void* d_out, int out_size, void* d_ws, size_t ws_size,
                              hipStream_t stream) {
    const float* spatial  = (const float*)d_in[0];
    const float* temporal = (const float*)d_in[1];
    float* out = (float*)d_out;

    if (d_ws != nullptr && ws_size >= WS_NEED) {
        unsigned short* ws = (unsigned short*)d_ws;
        {
            dim3 block(256);
            dim3 grid((Bsz * NG * 4 * 64) / 256);   // 1152 blocks
            convert_kernel<<<grid, block, 0, stream>>>(spatial, temporal, ws);
        }
        {
            dim3 block(256);
            dim3 grid(16 * NG32 * 2);               // 2240 flat blocks
            stgraph_rowpanel<<<grid, block, 0, stream>>>(ws, out);
        }
    } else {
        dim3 block(256);
        dim3 grid(NPAIR, Bsz);
        stgraph_fallback<<<grid, block, 0, stream>>>(spatial, temporal, out);
    }
}